// Round 7
// baseline (476.494 us; speedup 1.0000x reference)
//
#include <hip/hip_runtime.h>

// WECT R6. lane = direction (64 dirs per wave) -> every LDS wave-atomic hits
// 64 DISTINCT addresses (hist[lane][bin]) -> no same-address serialization.
// (R4/R5 invariant 334us = 64M lane-atomics with dir uniform across the wave
//  -> up-to-64-way same-address pileups at the per-CU LDS unit.)
// Table: u8 bin per (vertex,dir), 64B row per vertex (12.8MB), gather = one
// coalesced line per endpoint. Edge/tri indices+weights via wave-uniform
// scalar loads. U=8 batches -> 16-24 lines in flight per wave; 2 blocks/CU
// (64KB hist) x 1024 thr -> 32 waves/CU.
// Flush: per-block partial hist -> ws (plain stores), fused reduce+cumsum.

#define HGT 256
#define NDIR 64
#define NBINS (HGT * NDIR)
#define VTPB 1024
#define STPB 1024
#define VGRID 256
#define SGRID 512
#define UVB 4
#define UB 8
#define UTB 8

__global__ void wect_maxnorm(const float* __restrict__ vc, int k0,
                             unsigned* __restrict__ maxbits) {
    float m = 0.f;
    for (int i = blockIdx.x * blockDim.x + threadIdx.x; i < k0;
         i += gridDim.x * blockDim.x) {
        float x = vc[3 * i], y = vc[3 * i + 1], z = vc[3 * i + 2];
        m = fmaxf(m, sqrtf(x * x + y * y + z * z));
    }
    for (int off = 32; off > 0; off >>= 1)
        m = fmaxf(m, __shfl_down(m, off, 64));
    __shared__ float sm[16];
    int wid = threadIdx.x >> 6, lane = threadIdx.x & 63;
    if (lane == 0) sm[wid] = m;
    __syncthreads();
    if (threadIdx.x == 0) {
        float b = sm[0];
        int nw = blockDim.x >> 6;
        for (int w = 1; w < nw; ++w) b = fmaxf(b, sm[w]);
        atomicMax(maxbits, __float_as_uint(b));  // valid: all values >= 0
    }
}

__device__ __forceinline__ int height_bin(float h, float mh, float inv) {
    int idx = (int)ceilf((255.0f * (mh + h)) * inv);
    return min(max(idx, 0), HGT - 1);
}

// hist flat layout == out layout: [dir][height]
template <bool PART>
__device__ __forceinline__ void flush2(const float* hist, float* dst, int tpb) {
    if (PART) {
        float* slot = dst + (size_t)blockIdx.x * NBINS;
        for (int t = threadIdx.x; t < NBINS; t += tpb) slot[t] = hist[t];
    } else {
        for (int t = threadIdx.x; t < NBINS; t += tpb) {
            float v = hist[t];
            if (v != 0.f) atomicAdd(&dst[t], v);
        }
    }
}

template <bool PART>
__global__ __launch_bounds__(VTPB) void wect_vertex2(
    const float* __restrict__ vc, const float* __restrict__ vw,
    const float* __restrict__ dirs, int k0,
    const unsigned* __restrict__ maxbits, unsigned char* __restrict__ tab,
    float* __restrict__ dst) {
    __shared__ float hist[NDIR][HGT];
    int tid = threadIdx.x, lane = tid & 63;
    for (int t = tid; t < NBINS; t += VTPB) ((float*)hist)[t] = 0.f;
    float d0 = dirs[lane * 3], d1 = dirs[lane * 3 + 1], d2 = dirs[lane * 3 + 2];
    float mh = __uint_as_float(*maxbits);
    float inv = 1.0f / (2.0f * mh);
    __syncthreads();
    int wid = __builtin_amdgcn_readfirstlane((blockIdx.x * VTPB + tid) >> 6);
    int nw = (gridDim.x * VTPB) >> 6;
    for (int s0 = wid * UVB; s0 < k0; s0 += nw * UVB) {
        float x[UVB], y[UVB], z[UVB], w[UVB];
#pragma unroll
        for (int j = 0; j < UVB; ++j) {
            int s = min(s0 + j, k0 - 1);
            x[j] = vc[3 * s];
            y[j] = vc[3 * s + 1];
            z[j] = vc[3 * s + 2];
            w[j] = (s0 + j < k0) ? vw[s] : 0.f;
        }
#pragma unroll
        for (int j = 0; j < UVB; ++j) {
            int s = min(s0 + j, k0 - 1);
            float h = fmaf(x[j], d0, fmaf(y[j], d1, z[j] * d2));
            int b = height_bin(h, mh, inv);
            tab[(size_t)s * 64 + lane] = (unsigned char)b;
            atomicAdd(&hist[lane][b], w[j]);
        }
    }
    __syncthreads();
    flush2<PART>((const float*)hist, dst, VTPB);
}

template <bool PART>
__global__ __launch_bounds__(STPB) void wect_simplex2(
    const int2* __restrict__ edges, const float* __restrict__ ew,
    const int* __restrict__ tris, const float* __restrict__ tw, int k1, int k2,
    const unsigned char* __restrict__ tab, float* __restrict__ dst) {
    __shared__ float hist[NDIR][HGT];
    int tid = threadIdx.x, lane = tid & 63;
    for (int t = tid; t < NBINS; t += STPB) ((float*)hist)[t] = 0.f;
    __syncthreads();
    int wid = __builtin_amdgcn_readfirstlane((blockIdx.x * STPB + tid) >> 6);
    int nw = (gridDim.x * STPB) >> 6;

    // ---- edges: +w, max over 2 endpoints ----
    for (int s0 = wid * UB; s0 < k1; s0 += nw * UB) {
        int va[UB], vb[UB];
        float w[UB];
#pragma unroll
        for (int j = 0; j < UB; ++j) {
            int s = min(s0 + j, k1 - 1);  // uniform -> scalar loads
            int2 e = edges[s];
            va[j] = e.x;
            vb[j] = e.y;
            w[j] = (s0 + j < k1) ? ew[s] : 0.f;
        }
        unsigned A[UB], B[UB];
#pragma unroll
        for (int j = 0; j < UB; ++j) {
            A[j] = tab[(size_t)va[j] * 64 + lane];
            B[j] = tab[(size_t)vb[j] * 64 + lane];
        }
#pragma unroll
        for (int j = 0; j < UB; ++j) {
            int m = max((int)A[j], (int)B[j]);
            atomicAdd(&hist[lane][m], w[j]);
        }
    }

    // ---- triangles: -w, max over 3 endpoints ----
    for (int s0 = wid * UTB; s0 < k2; s0 += nw * UTB) {
        int v0[UTB], v1[UTB], v2[UTB];
        float w[UTB];
#pragma unroll
        for (int j = 0; j < UTB; ++j) {
            int s = min(s0 + j, k2 - 1);  // uniform -> scalar loads
            v0[j] = tris[3 * s];
            v1[j] = tris[3 * s + 1];
            v2[j] = tris[3 * s + 2];
            w[j] = (s0 + j < k2) ? tw[s] : 0.f;
        }
        unsigned A[UTB], B[UTB], C[UTB];
#pragma unroll
        for (int j = 0; j < UTB; ++j) {
            A[j] = tab[(size_t)v0[j] * 64 + lane];
            B[j] = tab[(size_t)v1[j] * 64 + lane];
            C[j] = tab[(size_t)v2[j] * 64 + lane];
        }
#pragma unroll
        for (int j = 0; j < UTB; ++j) {
            int m = max((int)A[j], max((int)B[j], (int)C[j]));
            atomicAdd(&hist[lane][m], -w[j]);
        }
    }

    __syncthreads();
    flush2<PART>((const float*)hist, dst, STPB);
}

// Sum partial histograms (nslots x NBINS) and cumsum over heights -> out.
__global__ __launch_bounds__(1024) void wect_reduce_cumsum(
    const float* __restrict__ part, int nslots, float* __restrict__ out) {
    __shared__ float lds[4 * HGT];
    int d = blockIdx.x;
    int tid = threadIdx.x;
    int b = tid & 255, g = tid >> 8;
    float acc = 0.f;
    for (int p = g; p < nslots; p += 4)
        acc += part[(size_t)p * NBINS + d * HGT + b];
    lds[tid] = acc;
    __syncthreads();
    float s = 0.f;
    if (tid < 256)
        s = lds[tid] + lds[tid + 256] + lds[tid + 512] + lds[tid + 768];
    __syncthreads();
    if (tid < 256) lds[tid] = s;
    __syncthreads();
    for (int off = 1; off < 256; off <<= 1) {
        float t = 0.f;
        if (tid < 256 && tid >= off) t = lds[tid - off];
        __syncthreads();
        if (tid < 256) lds[tid] += t;
        __syncthreads();
    }
    if (tid < 256) out[d * HGT + tid] = lds[tid];
}

// cumsum for the atomic-flush fallback path
__global__ void wect_cumsum(float* __restrict__ out) {
    int lane = threadIdx.x;
    float4* row = (float4*)out + (size_t)blockIdx.x * 64;
    float4 v = row[lane];
    v.y += v.x;
    v.z += v.y;
    v.w += v.z;
    float s = v.w;
    float mine = s;
    for (int off = 1; off < 64; off <<= 1) {
        float t = __shfl_up(s, off, 64);
        if (lane >= off) s += t;
    }
    float excl = s - mine;
    v.x += excl;
    v.y += excl;
    v.z += excl;
    v.w += excl;
    row[lane] = v;
}

// ---------------- fallback kernels (no workspace table) ----------------

__global__ __launch_bounds__(512) void wect_simplex_rec(
    const int* __restrict__ edges, const float* __restrict__ ew,
    const int* __restrict__ tris, const float* __restrict__ tw, int k1, int k2,
    const float* __restrict__ vc, const float* __restrict__ dirs,
    const unsigned* __restrict__ maxbits, float* __restrict__ out) {
    __shared__ float hist[NBINS];
    for (int i = threadIdx.x; i < NBINS; i += blockDim.x) hist[i] = 0.f;
    int lane = threadIdx.x & 63;
    float d0 = dirs[lane * 3], d1 = dirs[lane * 3 + 1], d2 = dirs[lane * 3 + 2];
    float mh = __uint_as_float(*maxbits);
    float inv = 1.0f / (2.0f * mh);
    __syncthreads();
    int wid = (blockIdx.x * blockDim.x + threadIdx.x) >> 6;
    int nw = (gridDim.x * blockDim.x) >> 6;
    int total = k1 + k2;
    for (int s = wid; s < total; s += nw) {
        int idx;
        float w;
        if (s < k1) {
            int v0 = edges[2 * s], v1 = edges[2 * s + 1];
            float h0 = vc[3 * v0] * d0 + vc[3 * v0 + 1] * d1 + vc[3 * v0 + 2] * d2;
            float h1 = vc[3 * v1] * d0 + vc[3 * v1 + 1] * d1 + vc[3 * v1 + 2] * d2;
            idx = max(height_bin(h0, mh, inv), height_bin(h1, mh, inv));
            w = ew[s];
        } else {
            int t = s - k1;
            int v0 = tris[3 * t], v1 = tris[3 * t + 1], v2 = tris[3 * t + 2];
            float h0 = vc[3 * v0] * d0 + vc[3 * v0 + 1] * d1 + vc[3 * v0 + 2] * d2;
            float h1 = vc[3 * v1] * d0 + vc[3 * v1 + 1] * d1 + vc[3 * v1 + 2] * d2;
            float h2 = vc[3 * v2] * d0 + vc[3 * v2 + 1] * d1 + vc[3 * v2 + 2] * d2;
            idx = max(height_bin(h0, mh, inv),
                      max(height_bin(h1, mh, inv), height_bin(h2, mh, inv)));
            w = -tw[t];
        }
        atomicAdd(&hist[idx * NDIR + lane], w);
    }
    __syncthreads();
    for (int i = threadIdx.x; i < NBINS; i += blockDim.x) {
        float v = hist[i];
        if (v != 0.f) atomicAdd(&out[(i & 63) * HGT + (i >> 6)], v);
    }
}

__global__ __launch_bounds__(512) void wect_vertex_rec(
    const float* __restrict__ vc, const float* __restrict__ vw,
    const float* __restrict__ dirs, int k0,
    const unsigned* __restrict__ maxbits, float* __restrict__ out) {
    __shared__ float hist[NBINS];
    for (int i = threadIdx.x; i < NBINS; i += blockDim.x) hist[i] = 0.f;
    int lane = threadIdx.x & 63;
    float d0 = dirs[lane * 3], d1 = dirs[lane * 3 + 1], d2 = dirs[lane * 3 + 2];
    float mh = __uint_as_float(*maxbits);
    float inv = 1.0f / (2.0f * mh);
    __syncthreads();
    int wid = (blockIdx.x * blockDim.x + threadIdx.x) >> 6;
    int nw = (gridDim.x * blockDim.x) >> 6;
    for (int k = wid; k < k0; k += nw) {
        float h = vc[3 * k] * d0 + vc[3 * k + 1] * d1 + vc[3 * k + 2] * d2;
        int idx = height_bin(h, mh, inv);
        atomicAdd(&hist[idx * NDIR + lane], vw[k]);
    }
    __syncthreads();
    for (int i = threadIdx.x; i < NBINS; i += blockDim.x) {
        float v = hist[i];
        if (v != 0.f) atomicAdd(&out[(i & 63) * HGT + (i >> 6)], v);
    }
}

extern "C" void kernel_launch(void* const* d_in, const int* in_sizes, int n_in,
                              void* d_out, int out_size, void* d_ws,
                              size_t ws_size, hipStream_t stream) {
    const float* v_coords = (const float*)d_in[0];
    const float* v_weights = (const float*)d_in[1];
    const int* edges = (const int*)d_in[2];
    const float* e_weights = (const float*)d_in[3];
    const int* tris = (const int*)d_in[4];
    const float* t_weights = (const float*)d_in[5];
    const float* dirs = (const float*)d_in[6];
    // d_in[7] = num_heights (=256, hardcoded as HGT)

    int k0 = in_sizes[0] / 3;
    int k1 = in_sizes[2] / 2;
    int k2 = in_sizes[4] / 3;

    float* out = (float*)d_out;
    unsigned* maxbits = (unsigned*)d_ws;
    unsigned char* tab = (unsigned char*)d_ws + 64;

    size_t table_need = 64 + (size_t)k0 * 64;
    size_t part_off = (table_need + 255) & ~(size_t)255;
    size_t part_need =
        part_off + (size_t)(VGRID + SGRID) * NBINS * sizeof(float);
    float* part = (float*)((char*)d_ws + part_off);

    (void)hipMemsetAsync(d_ws, 0, 64, stream);

    wect_maxnorm<<<256, 256, 0, stream>>>(v_coords, k0, maxbits);

    if (ws_size >= part_need) {
        wect_vertex2<true><<<VGRID, VTPB, 0, stream>>>(
            v_coords, v_weights, dirs, k0, maxbits, tab, part);
        wect_simplex2<true><<<SGRID, STPB, 0, stream>>>(
            (const int2*)edges, e_weights, tris, t_weights, k1, k2, tab,
            part + (size_t)VGRID * NBINS);
        wect_reduce_cumsum<<<NDIR, 1024, 0, stream>>>(part, VGRID + SGRID,
                                                      out);
    } else if (ws_size >= table_need) {
        (void)hipMemsetAsync(d_out, 0, (size_t)NBINS * sizeof(float), stream);
        wect_vertex2<false><<<VGRID, VTPB, 0, stream>>>(
            v_coords, v_weights, dirs, k0, maxbits, tab, out);
        wect_simplex2<false><<<SGRID, STPB, 0, stream>>>(
            (const int2*)edges, e_weights, tris, t_weights, k1, k2, tab, out);
        wect_cumsum<<<NDIR, 64, 0, stream>>>(out);
    } else {
        (void)hipMemsetAsync(d_out, 0, (size_t)NBINS * sizeof(float), stream);
        wect_vertex_rec<<<512, 512, 0, stream>>>(v_coords, v_weights, dirs, k0,
                                                 maxbits, out);
        wect_simplex_rec<<<512, 512, 0, stream>>>(edges, e_weights, tris,
                                                  t_weights, k1, k2, v_coords,
                                                  dirs, maxbits, out);
        wect_cumsum<<<NDIR, 64, 0, stream>>>(out);
    }
}